// Round 6
// baseline (788.867 us; speedup 1.0000x reference)
//
#include <hip/hip_runtime.h>

#define NNODES 200000
#define NEDGES 3200000
#define NGRAPH 100
#define NPG    2000
#define D      128
#define DOUT   64
#define CAP1   4096     // max distinct layer-1 nodes (expected ~1600)
#define CAP2   8192     // max edges into fetched nodes (expected ~1600)
#define CAPE   65536    // max edges into S1 nodes (expected ~25600)
#define FBUF   1024     // per-block LDS compaction buffer (expected ~2-30/block)
#define NBLK   1024     // 4 blocks/CU x 256 CUs -> co-resident with launch_bounds(256,4)
#define NTHR   256
#define BLINES 16       // barrier counter lines

// ---- init kernel: separate launch so barrier/counter cells are zero before mega ----
__global__ void prek(int* deg, int* s1idx, unsigned char* need,
                     float* agg1, float* agg2, int* cnt, int* bar) {
    int n = blockIdx.x * blockDim.x + threadIdx.x;   // grid covers 524288
    if (n < NNODES) { deg[n] = 0; s1idx[n] = -1; need[n] = 0; }
    if (n < CAP1 * D) agg1[n] = 0.0f;                // 524288 exactly
    if (n < NGRAPH * D) agg2[n] = 0.0f;
    if (n < 8) cnt[n] = 0;
    if (n < 7 * BLINES * 16) bar[n] = 0;
}

// ---- software grid barrier: BLINES counter lines, 1 atomic per block ----
__device__ __forceinline__ void gridbar(int* bar, int bi) {
    __syncthreads();
    if (threadIdx.x == 0) {
        __threadfence();                              // release
        atomicAdd(&bar[bi * BLINES * 16 + (blockIdx.x & (BLINES - 1)) * 16], 1);
        int s;
        do {
            s = 0;
            #pragma unroll
            for (int i = 0; i < BLINES; i++)
                s += __hip_atomic_load(&bar[bi * BLINES * 16 + i * 16],
                                       __ATOMIC_RELAXED, __HIP_MEMORY_SCOPE_AGENT);
            if (s < NBLK) __builtin_amdgcn_s_sleep(4);
        } while (s < NBLK);
    }
    __syncthreads();
    __threadfence();                                  // acquire
}

__global__ __launch_bounds__(NTHR, 4) void mega(
        const float* __restrict__ feat, const int* __restrict__ src,
        const int4* __restrict__ dst4, const int* __restrict__ to_fetch,
        const float* __restrict__ w1, const float* __restrict__ b1,
        const float* __restrict__ w2, const float* __restrict__ b2,
        const float* __restrict__ w3, const float* __restrict__ b3,
        float* __restrict__ out,
        int* deg, int* s1idx, unsigned char* need,
        int* s1nodes, int* e2src, int* e2slot, int* e1src, int* e1j,
        float* agg1, float* h1n, float* agg2, int* cnt, int* bar) {

    const int tid = threadIdx.x;
    const int bid = blockIdx.x;
    const int gid = bid * NTHR + tid;
    const int NV = NEDGES / 4;

    __shared__ int tf[NGRAPH];
    __shared__ int lcnt, lbase;
    __shared__ int bufs[FBUF], bufj[FBUF];
    __shared__ float sa[8][D];

    // ================= stage A: edges into fetched nodes, mark S1 sources =========
    for (int i = tid; i < NGRAPH; i += NTHR) tf[i] = to_fetch[i];
    if (tid == 0) lcnt = 0;
    __syncthreads();
    for (int v = gid; v < NV; v += NBLK * NTHR) {
        int4 d4 = dst4[v];
        int ds[4] = {d4.x, d4.y, d4.z, d4.w};
        #pragma unroll
        for (int q = 0; q < 4; ++q) {
            int d = ds[q];
            int slot = d / NPG;
            if (tf[slot] == d - slot * NPG) {
                int s = src[v * 4 + q];
                s1idx[s] = -2;                        // benign race, all write -2
                int p = atomicAdd(&lcnt, 1);
                if (p < FBUF) { bufs[p] = s; bufj[p] = slot; }
            }
        }
    }
    __syncthreads();
    {
        int n = min(lcnt, FBUF);
        if (tid == 0) lbase = atomicAdd(&cnt[0], n);
        __syncthreads();
        for (int k = tid; k < n; k += NTHR) {
            int g = lbase + k;
            if (g < CAP2) { e2src[g] = bufs[k]; e2slot[g] = bufj[k]; }
        }
        __syncthreads();
        if (tid == 0) lcnt = 0;
    }
    gridbar(bar, 0);

    // ================= stage compact: dedup S1 sources, assign dense ids ==========
    {
        int n2 = min(cnt[0], CAP2);
        if (bid == 0 && tid < NGRAPH) need[tf[tid] + tid * NPG] = 1;
        for (int k = gid; k < n2; k += NBLK * NTHR) {
            int s = e2src[k];
            bool win = (atomicCAS(&s1idx[s], -2, -4) == -2);
            unsigned long long mask = __ballot(win ? 1 : 0);
            if (mask) {
                int lane = tid & 63;
                int lead = __ffsll(mask) - 1;
                int nw = __popcll(mask);
                int base = 0;
                if (lane == lead) base = atomicAdd(&cnt[1], nw);
                base = __shfl(base, lead, 64);
                if (win) {
                    int idx = base + __popcll(mask & ((1ull << lane) - 1ull));
                    if (idx < CAP1) { s1idx[s] = idx; s1nodes[idx] = s; need[s] = 1; }
                    else s1idx[s] = -1;
                }
            }
        }
    }
    gridbar(bar, 1);

    // ================= stage B: edges into S1 nodes, mark sources needed ==========
    for (int v = gid; v < NV; v += NBLK * NTHR) {
        int4 d4 = dst4[v];
        int ds[4] = {d4.x, d4.y, d4.z, d4.w};
        #pragma unroll
        for (int q = 0; q < 4; ++q) {
            int j = s1idx[ds[q]];
            if (j >= 0) {
                int s = src[v * 4 + q];
                need[s] = 1;                          // benign race
                int p = atomicAdd(&lcnt, 1);
                if (p < FBUF) { bufs[p] = s; bufj[p] = j; }
            }
        }
    }
    __syncthreads();
    {
        int n = min(lcnt, FBUF);
        if (tid == 0) lbase = atomicAdd(&cnt[2], n);
        __syncthreads();
        for (int k = tid; k < n; k += NTHR) {
            int g = lbase + k;
            if (g < CAPE) { e1src[g] = bufs[k]; e1j[g] = bufj[k]; }
        }
    }
    gridbar(bar, 2);

    // ================= stage C: degrees of needed nodes only ======================
    for (int v = gid; v < NV; v += NBLK * NTHR) {
        int4 d4 = dst4[v];
        int ds[4] = {d4.x, d4.y, d4.z, d4.w};
        #pragma unroll
        for (int q = 0; q < 4; ++q)
            if (need[ds[q]]) atomicAdd(&deg[ds[q]], 1);
    }
    gridbar(bar, 3);

    // ================= stage agg1: agg1[j] += feat[s]*norm[s] =====================
    {
        int ne = min(cnt[2], CAPE);
        int col = tid & 127, sub = tid >> 7;          // 2 edge-lanes per block
        for (int e = bid * 2 + sub; e < ne; e += NBLK * 2) {
            int s = e1src[e];
            float v = feat[(size_t)s * D + col] * rsqrtf(fmaxf((float)deg[s], 1.0f));
            atomicAdd(&agg1[e1j[e] * D + col], v);
        }
    }
    gridbar(bar, 4);

    // ================= stage gemm1: h1n = relu((agg1@w1)*nm+b1)*nm, 8 rows/block ==
    {
        int nj = min(cnt[1], CAP1);
        int col = tid & 127, half = tid >> 7;
        for (int g = bid; g * 8 < nj; g += NBLK) {
            __syncthreads();
            for (int x = tid; x < 8 * D; x += NTHR) {
                int r = x >> 7, c = x & 127, row = g * 8 + r;
                sa[r][c] = (row < nj) ? agg1[row * D + c] : 0.0f;
            }
            __syncthreads();
            int r0 = half * 4;
            float a0 = 0, a1 = 0, a2 = 0, a3 = 0;
            #pragma unroll 4
            for (int k = 0; k < D; k++) {
                float w = w1[k * D + col];
                a0 += sa[r0 + 0][k] * w; a1 += sa[r0 + 1][k] * w;
                a2 += sa[r0 + 2][k] * w; a3 += sa[r0 + 3][k] * w;
            }
            float bb = b1[col];
            float accs[4] = {a0, a1, a2, a3};
            #pragma unroll
            for (int i = 0; i < 4; i++) {
                int row = g * 8 + r0 + i;
                if (row < nj) {
                    float nm = rsqrtf(fmaxf((float)deg[s1nodes[row]], 1.0f));
                    h1n[row * D + col] = fmaxf(accs[i] * nm + bb, 0.0f) * nm;
                }
            }
        }
    }
    gridbar(bar, 5);

    // ================= stage agg2: agg2[slot] += h1n[s1idx[src]] ==================
    {
        int n2 = min(cnt[0], CAP2);
        int col = tid & 127, sub = tid >> 7;
        for (int e = bid * 2 + sub; e < n2; e += NBLK * 2) {
            int j = s1idx[e2src[e]];
            if (j >= 0) atomicAdd(&agg2[e2slot[e] * D + col], h1n[j * D + col]);
        }
    }
    gridbar(bar, 6);

    // ================= stage final: h2 = relu((agg2@w2)*nm+b2); out = h2@w3^T+b3 ==
    if (bid < NGRAPH) {
        int i = bid;
        __shared__ float sv[D], h2[D];
        if (tid < D) sv[tid] = agg2[i * D + tid];
        __syncthreads();
        if (tid < D) {
            float acc = 0.0f;
            #pragma unroll 4
            for (int k = 0; k < D; k++) acc += sv[k] * w2[k * D + tid];
            float nm = rsqrtf(fmaxf((float)deg[tf[i] + i * NPG], 1.0f));
            h2[tid] = fmaxf(acc * nm + b2[tid], 0.0f);
        }
        __syncthreads();
        if (tid < DOUT) {
            float o = 0.0f;
            #pragma unroll 4
            for (int k = 0; k < D; k++) o += h2[k] * w3[tid * D + k];
            out[i * DOUT + tid] = o + b3[tid];
        }
    }
}

extern "C" void kernel_launch(void* const* d_in, const int* in_sizes, int n_in,
                              void* d_out, int out_size, void* d_ws, size_t ws_size,
                              hipStream_t stream) {
    const float* feat     = (const float*)d_in[0];
    const int*   src      = (const int*)  d_in[1];
    const int*   dst      = (const int*)  d_in[2];
    const int*   to_fetch = (const int*)  d_in[3];
    const float* w1       = (const float*)d_in[4];
    const float* b1       = (const float*)d_in[5];
    const float* w2       = (const float*)d_in[6];
    const float* b2       = (const float*)d_in[7];
    const float* w3       = (const float*)d_in[8];
    const float* b3       = (const float*)d_in[9];
    float* out = (float*)d_out;
    const int4* dst4 = (const int4*)dst;

    // workspace layout
    char* p = (char*)d_ws;
    int*   deg     = (int*)p;            p += (size_t)NNODES * 4;
    int*   s1idx   = (int*)p;            p += (size_t)NNODES * 4;
    int*   s1nodes = (int*)p;            p += (size_t)CAP1 * 4;
    int*   e2src   = (int*)p;            p += (size_t)CAP2 * 4;
    int*   e2slot  = (int*)p;            p += (size_t)CAP2 * 4;
    int*   e1src   = (int*)p;            p += (size_t)CAPE * 4;
    int*   e1j     = (int*)p;            p += (size_t)CAPE * 4;
    float* agg1    = (float*)p;          p += (size_t)CAP1 * D * 4;
    float* h1n     = (float*)p;          p += (size_t)CAP1 * D * 4;
    float* agg2    = (float*)p;          p += (size_t)NGRAPH * D * 4;
    int*   cnt     = (int*)p;            p += 64;
    int*   bar     = (int*)p;            p += 7 * BLINES * 16 * 4;
    unsigned char* need = (unsigned char*)p; p += (size_t)NNODES;

    prek<<<(CAP1 * D + 255) / 256, 256, 0, stream>>>(deg, s1idx, need, agg1, agg2, cnt, bar);
    mega<<<NBLK, NTHR, 0, stream>>>(feat, src, dst4, to_fetch, w1, b1, w2, b2, w3, b3,
                                    out, deg, s1idx, need, s1nodes, e2src, e2slot,
                                    e1src, e1j, agg1, h1n, agg2, cnt, bar);
}

// Round 7
// 168.039 us; speedup vs baseline: 4.6945x; 4.6945x over previous
//
#include <hip/hip_runtime.h>

#define NNODES 200000
#define NEDGES 3200000
#define NGRAPH 100
#define NPG    2000
#define D      128
#define DOUT   64
#define CAP1   4096     // max distinct layer-1 nodes (expected ~1600)
#define CAP2   8192     // max edges into fetched nodes (expected ~1600)
#define CAPE   65536    // max edges into S1 nodes (expected ~25600)
#define FBUF   1024     // per-block LDS compaction buffer

// ---- init: zero deg/need/counters/agg1, -1 the s1 index map ----
__global__ void prek(int* deg, int* s1idx, unsigned char* need, float* agg1, int* cnt) {
    int n = blockIdx.x * blockDim.x + threadIdx.x;   // grid covers 524288
    if (n < NNODES) { deg[n] = 0; s1idx[n] = -1; need[n] = 0; }
    if (n < CAP1 * D) agg1[n] = 0.0f;
    if (n < 8) cnt[n] = 0;
}

// ---- pass A+compact: edges into fetched nodes (arithmetic membership),
//      collect (src,slot) via LDS compaction, inline-dedup sources into S1 ----
__global__ void passAC(const int* __restrict__ src, const int4* __restrict__ dst4,
                       const int* __restrict__ to_fetch,
                       int* e2src, int* e2slot, int* s1idx, int* s1nodes,
                       unsigned char* need, int* cnt) {
    __shared__ int tf[NGRAPH];
    __shared__ int lcnt, lbase;
    __shared__ int bufs[FBUF], bufj[FBUF];
    int tid = threadIdx.x;
    for (int i = tid; i < NGRAPH; i += blockDim.x) tf[i] = to_fetch[i];
    if (blockIdx.x == 0 && tid < NGRAPH) need[to_fetch[tid] + tid * NPG] = 1;
    if (tid == 0) lcnt = 0;
    __syncthreads();
    const int NV = NEDGES / 4;
    int stride = gridDim.x * blockDim.x;
    for (int v = blockIdx.x * blockDim.x + tid; v < NV; v += stride) {
        int4 d4 = dst4[v];
        int ds[4] = {d4.x, d4.y, d4.z, d4.w};
        #pragma unroll
        for (int q = 0; q < 4; ++q) {
            int d = ds[q];
            int slot = d / NPG;                       // magic-mul division
            if (tf[slot] == d - slot * NPG) {
                int s = src[v * 4 + q];
                // append edge record
                int p = atomicAdd(&lcnt, 1);
                if (p < FBUF) { bufs[p] = s; bufj[p] = slot; }
                // inline dedup: claim s as S1 node
                bool win = (atomicCAS(&s1idx[s], -1, -2) == -1);
                unsigned long long mask = __ballot(win ? 1 : 0);
                if (mask) {
                    int lane = tid & 63;
                    int lead = __ffsll(mask) - 1;
                    int nw = __popcll(mask);
                    int base = 0;
                    if (lane == lead) base = atomicAdd(&cnt[1], nw);
                    base = __shfl(base, lead, 64);
                    if (win) {
                        int idx = base + __popcll(mask & ((1ull << lane) - 1ull));
                        if (idx < CAP1) { s1idx[s] = idx; s1nodes[idx] = s; need[s] = 1; }
                        else s1idx[s] = -1;
                    }
                }
            }
        }
    }
    __syncthreads();
    {
        int n = min(lcnt, FBUF);
        if (tid == 0) lbase = atomicAdd(&cnt[0], n);
        __syncthreads();
        for (int k = tid; k < n; k += blockDim.x) {
            int g = lbase + k;
            if (g < CAP2) { e2src[g] = bufs[k]; e2slot[g] = bufj[k]; }
        }
    }
}

// ---- pass B: collect edges into S1 nodes; flag their sources as needed ----
__global__ void passB(const int* __restrict__ src, const int4* __restrict__ dst4,
                      const int* __restrict__ s1idx, unsigned char* need,
                      int* e1src, int* e1j, int* cnt) {
    __shared__ int lcnt, lbase;
    __shared__ int bufs[FBUF], bufj[FBUF];
    int tid = threadIdx.x;
    if (tid == 0) lcnt = 0;
    __syncthreads();
    const int NV = NEDGES / 4;
    int stride = gridDim.x * blockDim.x;
    int iters = (NV + stride - 1) / stride;
    int v0 = blockIdx.x * blockDim.x + tid;
    for (int it = 0; it < iters; ++it) {
        int v = v0 + it * stride;
        if (v < NV) {
            int4 d4 = dst4[v];
            int ds[4] = {d4.x, d4.y, d4.z, d4.w};
            #pragma unroll
            for (int q = 0; q < 4; ++q) {
                int j = s1idx[ds[q]];
                if (j >= 0) {
                    int s = src[v * 4 + q];
                    need[s] = 1;                      // benign race
                    int p = atomicAdd(&lcnt, 1);
                    if (p < FBUF) { bufs[p] = s; bufj[p] = j; }
                }
            }
        }
        __syncthreads();
        if (lcnt > FBUF - 1024) {                     // safety flush (uniform)
            int n = min(lcnt, FBUF);
            if (tid == 0) lbase = atomicAdd(&cnt[2], n);
            __syncthreads();
            for (int k = tid; k < n; k += blockDim.x) {
                int g = lbase + k;
                if (g < CAPE) { e1src[g] = bufs[k]; e1j[g] = bufj[k]; }
            }
            __syncthreads();
            if (tid == 0) lcnt = 0;
            __syncthreads();
        }
    }
    int n = min(lcnt, FBUF);
    if (n > 0) {
        if (tid == 0) lbase = atomicAdd(&cnt[2], n);
        __syncthreads();
        for (int k = tid; k < n; k += blockDim.x) {
            int g = lbase + k;
            if (g < CAPE) { e1src[g] = bufs[k]; e1j[g] = bufj[k]; }
        }
    }
}

// ---- pass C: degree count, only for needed nodes (~27K of 200K) ----
__global__ void passC(const int4* __restrict__ dst4, const unsigned char* __restrict__ need,
                      int* deg) {
    const int NV = NEDGES / 4;
    int stride = gridDim.x * blockDim.x;
    for (int v = blockIdx.x * blockDim.x + threadIdx.x; v < NV; v += stride) {
        int4 d4 = dst4[v];
        int ds[4] = {d4.x, d4.y, d4.z, d4.w};
        #pragma unroll
        for (int q = 0; q < 4; ++q)
            if (need[ds[q]]) atomicAdd(&deg[ds[q]], 1);
    }
}

// ---- layer-1 aggregation: agg1[j] += feat[s]*rsqrt(max(deg[s],1)) ----
__global__ void agg1_kernel(const int* __restrict__ e1src, const int* __restrict__ e1j,
                            const int* __restrict__ cnt, const int* __restrict__ deg,
                            const float* __restrict__ feat, float* agg1) {
    int t = threadIdx.x;                 // 128
    int ne = min(cnt[2], CAPE);
    for (int e = blockIdx.x; e < ne; e += gridDim.x) {
        int s = e1src[e];
        float nm = rsqrtf(fmaxf((float)deg[s], 1.0f));
        float v = feat[(size_t)s * D + t] * nm;
        atomicAdd(&agg1[e1j[e] * D + t], v);
    }
}

// ---- layer-1 GEMM + relu + pre-multiply next-layer norm, 8 rows/block ----
__global__ void gemm1(const float* __restrict__ agg1, const float* __restrict__ w1,
                      const float* __restrict__ b1, const int* __restrict__ deg,
                      const int* __restrict__ s1nodes, const int* __restrict__ cnt,
                      float* h1n) {
    int nj = min(cnt[1], CAP1);
    int tid = threadIdx.x;               // 256
    int col = tid & 127, half = tid >> 7;
    __shared__ float sa[8][D];
    for (int g = blockIdx.x; g * 8 < nj; g += gridDim.x) {
        __syncthreads();
        for (int x = tid; x < 8 * D; x += blockDim.x) {
            int r = x >> 7, c = x & 127, row = g * 8 + r;
            sa[r][c] = (row < nj) ? agg1[row * D + c] : 0.0f;
        }
        __syncthreads();
        int r0 = half * 4;
        float a0 = 0, a1 = 0, a2 = 0, a3 = 0;
        #pragma unroll 4
        for (int k = 0; k < D; k++) {
            float w = w1[k * D + col];
            a0 += sa[r0 + 0][k] * w; a1 += sa[r0 + 1][k] * w;
            a2 += sa[r0 + 2][k] * w; a3 += sa[r0 + 3][k] * w;
        }
        float bb = b1[col];
        float accs[4] = {a0, a1, a2, a3};
        #pragma unroll
        for (int i = 0; i < 4; i++) {
            int row = g * 8 + r0 + i;
            if (row < nj) {
                float nm = rsqrtf(fmaxf((float)deg[s1nodes[row]], 1.0f));
                h1n[row * D + col] = fmaxf(accs[i] * nm + bb, 0.0f) * nm;
            }
        }
    }
}

// ---- fused agg2 + layer-2 GEMM + final projection: one block per graph ----
__global__ void agg2final(const int* __restrict__ e2src, const int* __restrict__ e2slot,
                          const int* __restrict__ s1idx, const int* __restrict__ cnt,
                          const float* __restrict__ h1n, const int* __restrict__ deg,
                          const int* __restrict__ to_fetch,
                          const float* __restrict__ w2, const float* __restrict__ b2,
                          const float* __restrict__ w3, const float* __restrict__ b3,
                          float* __restrict__ out) {
    int i = blockIdx.x;                  // 0..99
    int t = threadIdx.x;                 // 128
    __shared__ float sv[D], h2[D];
    __shared__ int lj[256];
    __shared__ int lc;
    if (t == 0) lc = 0;
    __syncthreads();
    int ne2 = min(cnt[0], CAP2);
    for (int e = t; e < ne2; e += blockDim.x) {       // parallel scan of edge list
        if (e2slot[e] == i) {
            int j = s1idx[e2src[e]];
            if (j >= 0) { int p = atomicAdd(&lc, 1); if (p < 256) lj[p] = j; }
        }
    }
    __syncthreads();
    int m = min(lc, 256);
    float acc = 0.0f;
    for (int k = 0; k < m; ++k) acc += h1n[lj[k] * D + t];
    sv[t] = acc;
    __syncthreads();
    float a2 = 0.0f;
    #pragma unroll 4
    for (int k = 0; k < D; k++) a2 += sv[k] * w2[k * D + t];
    float nm = rsqrtf(fmaxf((float)deg[to_fetch[i] + i * NPG], 1.0f));
    h2[t] = fmaxf(a2 * nm + b2[t], 0.0f);
    __syncthreads();
    if (t < DOUT) {
        float o = 0.0f;
        #pragma unroll 4
        for (int k = 0; k < D; k++) o += h2[k] * w3[t * D + k];
        out[i * DOUT + t] = o + b3[t];
    }
}

extern "C" void kernel_launch(void* const* d_in, const int* in_sizes, int n_in,
                              void* d_out, int out_size, void* d_ws, size_t ws_size,
                              hipStream_t stream) {
    const float* feat     = (const float*)d_in[0];
    const int*   src      = (const int*)  d_in[1];
    const int*   dst      = (const int*)  d_in[2];
    const int*   to_fetch = (const int*)  d_in[3];
    const float* w1       = (const float*)d_in[4];
    const float* b1       = (const float*)d_in[5];
    const float* w2       = (const float*)d_in[6];
    const float* b2       = (const float*)d_in[7];
    const float* w3       = (const float*)d_in[8];
    const float* b3       = (const float*)d_in[9];
    float* out = (float*)d_out;
    const int4* dst4 = (const int4*)dst;

    // workspace layout
    char* p = (char*)d_ws;
    int*   deg     = (int*)p;            p += (size_t)NNODES * 4;
    int*   s1idx   = (int*)p;            p += (size_t)NNODES * 4;
    int*   s1nodes = (int*)p;            p += (size_t)CAP1 * 4;
    int*   e2src   = (int*)p;            p += (size_t)CAP2 * 4;
    int*   e2slot  = (int*)p;            p += (size_t)CAP2 * 4;
    int*   e1src   = (int*)p;            p += (size_t)CAPE * 4;
    int*   e1j     = (int*)p;            p += (size_t)CAPE * 4;
    float* agg1    = (float*)p;          p += (size_t)CAP1 * D * 4;
    float* h1n     = (float*)p;          p += (size_t)CAP1 * D * 4;
    int*   cnt     = (int*)p;            p += 64;
    unsigned char* need = (unsigned char*)p; p += (size_t)NNODES;

    prek<<<(CAP1 * D + 255) / 256, 256, 0, stream>>>(deg, s1idx, need, agg1, cnt);
    passAC<<<2048, 256, 0, stream>>>(src, dst4, to_fetch, e2src, e2slot,
                                     s1idx, s1nodes, need, cnt);
    passB<<<2048, 256, 0, stream>>>(src, dst4, s1idx, need, e1src, e1j, cnt);
    passC<<<2048, 256, 0, stream>>>(dst4, need, deg);
    agg1_kernel<<<2048, 128, 0, stream>>>(e1src, e1j, cnt, deg, feat, agg1);
    gemm1<<<512, 256, 0, stream>>>(agg1, w1, b1, deg, s1nodes, cnt, h1n);
    agg2final<<<NGRAPH, 128, 0, stream>>>(e2src, e2slot, s1idx, cnt, h1n, deg,
                                          to_fetch, w2, b2, w3, b3, out);
}